// Round 8
// baseline (104.489 us; speedup 1.0000x reference)
//
#include <hip/hip_runtime.h>
#include <hip/hip_bf16.h>

#define DB 8
#define DT 2048
#define DC 1024
#define DH 128

typedef __attribute__((ext_vector_type(8))) short short8;
typedef __attribute__((ext_vector_type(4))) float f32x4;
typedef __attribute__((ext_vector_type(4))) int i32x4;
typedef __attribute__((ext_vector_type(4))) unsigned short u16x4;

// round-to-nearest-even f32 -> bf16 bits
static __device__ __forceinline__ unsigned short bfbits(float x){
    union { float f; unsigned u; } a; a.f = x;
    unsigned u = a.u;
    unsigned r = u + 0x7fffu + ((u >> 16) & 1u);
    return (unsigned short)(r >> 16);
}
static __device__ __forceinline__ unsigned pbf2(float lo, float hi){
    return (unsigned)bfbits(lo) | ((unsigned)bfbits(hi) << 16);
}

// Redistribute 32 kv-wide P slice (S^T D-layout words pk0..pk3) into the
// PV B-fragment layout (kv = 8g+i). Verified R0..R7.
static __device__ __forceinline__ short8 redist(unsigned pk0, unsigned pk1,
                                                unsigned pk2, unsigned pk3,
                                                int g, int c){
    const int src0 = c + (((2*g    ) & 3) << 4);
    const int src1 = c + (((2*g + 1) & 3) << 4);
    const int sel  = g >> 1;
    unsigned a0 = __shfl(pk0, src0), a2 = __shfl(pk2, src0);
    unsigned b0 = __shfl(pk1, src0), b2 = __shfl(pk3, src0);
    unsigned c0 = __shfl(pk0, src1), c2 = __shfl(pk2, src1);
    unsigned d0 = __shfl(pk1, src1), d2 = __shfl(pk3, src1);
    i32x4 pw = { (int)(sel ? a2 : a0), (int)(sel ? b2 : b0),
                 (int)(sel ? c2 : c0), (int)(sel ? d2 : d0) };
    return __builtin_bit_cast(short8, pw);
}

// WTc[t][chunk][n][e] = W_p[k][h] bf16, k = t*32 + chunk*8 + e, n = p*128+h.
__global__ __launch_bounds__(256) void prep_wt_kernel(const float* __restrict__ Wq,
                                                      const float* __restrict__ Wk,
                                                      const float* __restrict__ Wv,
                                                      unsigned short* __restrict__ WTc){
    int gid = blockIdx.x * 256 + threadIdx.x;      // 0 .. 393215
    int e  = gid & 7;
    int F3 = gid >> 3;
    int n  = F3 % 384;
    int ct = F3 / 384;                              // t*4 + chunk, 0..127
    int k  = (ct >> 2) * 32 + (ct & 3) * 8 + e;
    int p  = n >> 7, h = n & 127;
    const float* W = (p == 0) ? Wq : (p == 1 ? Wk : Wv);
    float v = W[(size_t)k * DH + h];
    if (p == 0) v *= 0.08838834764831845f * 1.4426950408889634f;  // H^-0.5 * log2(e)
    WTc[gid] = bfbits(v);
}

// Fused QKV projection v2 (unchanged from R7 passing version).
__global__ __launch_bounds__(512, 4) void qkv_kernel(const float* __restrict__ x,
                                                     const unsigned short* __restrict__ WTc,
                                                     unsigned short* __restrict__ Qb,
                                                     unsigned short* __restrict__ Kb,
                                                     unsigned short* __restrict__ VT){
    __shared__ unsigned short Bs[2][12288];   // 2 x 24KB
    __shared__ unsigned short As[2][2560];    // 2 x 5KB  (64 rows x stride 40)

    const int tid  = threadIdx.x;
    const int lane = tid & 63;
    const int w    = tid >> 6;
    const int g = lane >> 4, c = lane & 15;
    const int m0 = blockIdx.x * 64;
    const int n0 = w * 48;

    const unsigned short* bsrc = WTc + (size_t)tid * 8;
    const bool doA = tid < 256;
    const int arow = tid >> 2, ac8 = tid & 3;
    const float* asrc = x + (size_t)(m0 + arow) * DC + ac8 * 8;

    f32x4 acc[4][3] = {};
    i32x4 breg[3];
    float4 av0, av1;

#pragma unroll
    for (int j = 0; j < 3; ++j)
        breg[j] = *(const i32x4*)(bsrc + j * 4096);
    if (doA){ av0 = *(const float4*)asrc; av1 = *(const float4*)(asrc + 4); }
#pragma unroll
    for (int j = 0; j < 3; ++j)
        *(i32x4*)(&Bs[0][j * 4096 + tid * 8]) = breg[j];
    if (doA){
        i32x4 h8 = { (int)pbf2(av0.x, av0.y), (int)pbf2(av0.z, av0.w),
                     (int)pbf2(av1.x, av1.y), (int)pbf2(av1.z, av1.w) };
        *(i32x4*)(&As[0][arow * 40 + ac8 * 8]) = h8;
    }

    for (int t = 0; t < DC / 32; ++t){
        const int cur = t & 1;
        __syncthreads();
        if (t < DC / 32 - 1){
#pragma unroll
            for (int j = 0; j < 3; ++j)
                breg[j] = *(const i32x4*)(bsrc + (t + 1) * 12288 + j * 4096);
            if (doA){
                av0 = *(const float4*)(asrc + (t + 1) * 32);
                av1 = *(const float4*)(asrc + (t + 1) * 32 + 4);
            }
        }
        short8 af[4], bfr[3];
#pragma unroll
        for (int mf = 0; mf < 4; ++mf)
            af[mf] = *(const short8*)(&As[cur][(mf*16 + c) * 40 + g * 8]);
#pragma unroll
        for (int nf = 0; nf < 3; ++nf)
            bfr[nf] = *(const short8*)(&Bs[cur][g * 3072 + (n0 + nf*16 + c) * 8]);
#pragma unroll
        for (int mf = 0; mf < 4; ++mf)
#pragma unroll
            for (int nf = 0; nf < 3; ++nf)
                acc[mf][nf] = __builtin_amdgcn_mfma_f32_16x16x32_bf16(af[mf], bfr[nf], acc[mf][nf], 0, 0, 0);
        if (t < DC / 32 - 1){
#pragma unroll
            for (int j = 0; j < 3; ++j)
                *(i32x4*)(&Bs[cur ^ 1][j * 4096 + tid * 8]) = breg[j];
            if (doA){
                i32x4 h8 = { (int)pbf2(av0.x, av0.y), (int)pbf2(av0.z, av0.w),
                             (int)pbf2(av1.x, av1.y), (int)pbf2(av1.z, av1.w) };
                *(i32x4*)(&As[cur ^ 1][arow * 40 + ac8 * 8]) = h8;
            }
        }
    }

    const int bb = m0 >> 11;
    const int tb = m0 & 2047;
#pragma unroll
    for (int mf = 0; mf < 4; ++mf)
#pragma unroll
        for (int nf = 0; nf < 3; ++nf){
            const int n  = n0 + nf*16;
            const int p  = n >> 7;
            const int np = (n & 127) + c;
            const int row = m0 + mf*16 + 4*g;
            if (p < 2){
                unsigned short* O = (p == 0) ? Qb : Kb;   // [B*T][H]
#pragma unroll
                for (int r = 0; r < 4; ++r)
                    O[(size_t)(row + r) * DH + np] = bfbits(acc[mf][nf][r]);
            } else {
                const int t0 = tb + mf*16 + 4*g;
                u16x4 v = { bfbits(acc[mf][nf][0]), bfbits(acc[mf][nf][1]),
                            bfbits(acc[mf][nf][2]), bfbits(acc[mf][nf][3]) };
                *(u16x4*)(VT + ((size_t)bb * DH + np) * DT + t0) = v;
            }
        }
}

// Causal flash attention v3: pair-balanced blocks.
// 32-row q-tiles (64 per batch); block bi handles tiles pr and 63-pr of batch
// bi&7 -> every block does exactly 33 kv-iterations (KVBLK=64). Grid 256.
// Block = 128 threads (2 waves x 16 q-rows). K/V staged to swizzled LDS,
// double-buffered; defer-max (T13) skips acc rescale when max doesn't grow.
__global__ __launch_bounds__(128, 2) void attn_kernel(const unsigned short* __restrict__ Qb,
                                                      const unsigned short* __restrict__ Kb,
                                                      const unsigned short* __restrict__ VT,
                                                      float* __restrict__ out){
    __shared__ unsigned char lds[2][32768];   // per buf: K 16KB @0, V 16KB @16384

    const int tid  = threadIdx.x;
    const int lane = tid & 63;
    const int w    = tid >> 6;             // 0..1
    const int g = lane >> 4, c = lane & 15;
    const int bi = blockIdx.x;
    const int b  = bi & 7;                 // batch == XCD (bi % 8)
    const int pr = bi >> 3;                // pair index 0..31

    const unsigned short* Kbase = Kb + (size_t)b * DT * DH;
    const unsigned short* Vbase = VT + (size_t)b * DH * DT;

#pragma unroll
    for (int ph = 0; ph < 2; ++ph){
        const int tile = ph ? (63 - pr) : pr;   // 32-row q-tile index
        const int qw = tile * 32 + 16 * w;      // this wave's q base
        const int q  = qw + c;                  // this lane's q row
        const int nt = (tile >> 1) + 1;         // kv-iterations (KVBLK=64)

        short8 qf[4];
#pragma unroll
        for (int hc = 0; hc < 4; ++hc)
            qf[hc] = *(const short8*)(Qb + ((size_t)b*DT + qw + c) * DH + hc*32 + g*8);

        f32x4 acc[8] = {};
        float m = -1e30f, l = 0.f;

        i32x4 kreg[8], vreg[8];
        // all reads of the previous phase's LDS must be done before restaging
        __syncthreads();
        // ---- prologue: stage kv-tile 0 ----
#pragma unroll
        for (int p = 0; p < 8; ++p){
            const int s = p*128 + tid;
            kreg[p] = *(const i32x4*)(Kbase + (size_t)(s >> 4) * DH + (s & 15) * 8);
            vreg[p] = *(const i32x4*)(Vbase + (size_t)(s >> 3) * DT + (s & 7) * 8);
        }
#pragma unroll
        for (int p = 0; p < 8; ++p){
            const int s = p*128 + tid;
            const int r = s >> 4, cb = (s & 15) * 16;
            *(i32x4*)(lds[0] + r*256 + (cb ^ ((r & 7) << 4))) = kreg[p];
            const int h = s >> 3, tb = (s & 7) * 16;
            *(i32x4*)(lds[0] + 16384 + h*128 + (tb ^ ((h & 7) << 4))) = vreg[p];
        }

        for (int kt = 0; kt < nt; ++kt){
            const int cur = kt & 1;
            const int kv0 = kt * 64;
            __syncthreads();                      // buf[cur] staged & prior reads done

            // ---- issue next tile's global loads early (T14) ----
            if (kt < nt - 1){
                const int nv0 = kv0 + 64;
#pragma unroll
                for (int p = 0; p < 8; ++p){
                    const int s = p*128 + tid;
                    kreg[p] = *(const i32x4*)(Kbase + (size_t)(nv0 + (s >> 4)) * DH + (s & 15) * 8);
                    vreg[p] = *(const i32x4*)(Vbase + (size_t)(s >> 3) * DT + nv0 + (s & 7) * 8);
                }
            }

            const unsigned char* kb = lds[cur];
            const unsigned char* vb = lds[cur] + 16384;

            // ---- QK^T from LDS K ----
            f32x4 s4[4] = {};
            short8 kf[4][4];
#pragma unroll
            for (int j = 0; j < 4; ++j){
                const int r = 16*j + c;
#pragma unroll
                for (int hc = 0; hc < 4; ++hc)
                    kf[j][hc] = *(const short8*)(kb + r*256 + ((hc*64 + g*16) ^ ((r & 7) << 4)));
            }
            __builtin_amdgcn_s_setprio(1);
#pragma unroll
            for (int hc = 0; hc < 4; ++hc)
#pragma unroll
                for (int j = 0; j < 4; ++j)
                    s4[j] = __builtin_amdgcn_mfma_f32_16x16x32_bf16(kf[j][hc], qf[hc], s4[j], 0,0,0);
            __builtin_amdgcn_s_setprio(0);

            // ---- causal mask (last kv-iter of this tile only) ----
            if (kt == nt - 1){
#pragma unroll
                for (int j = 0; j < 4; ++j){
                    const int o = kv0 + 16*j + 4*g;
#pragma unroll
                    for (int r = 0; r < 4; ++r)
                        if (o + r > q) s4[j][r] = -1e30f;
                }
            }

            // ---- online softmax with defer-max (T13) ----
            float tm = -1e30f;
#pragma unroll
            for (int j = 0; j < 4; ++j)
#pragma unroll
                for (int r = 0; r < 4; ++r) tm = fmaxf(tm, s4[j][r]);
            tm = fmaxf(tm, __shfl_xor(tm, 16));
            tm = fmaxf(tm, __shfl_xor(tm, 32));
            if (!__all(tm <= m + 8.f)){
                const float mn = fmaxf(m, tm);
                const float rs = exp2f(m - mn);
                l *= rs;
#pragma unroll
                for (int mt = 0; mt < 8; ++mt) acc[mt] *= rs;
                m = mn;
            }
            float p[4][4]; float ps = 0.f;
#pragma unroll
            for (int j = 0; j < 4; ++j)
#pragma unroll
                for (int r = 0; r < 4; ++r){
                    p[j][r] = exp2f(s4[j][r] - m);
                    ps += p[j][r];
                }
            ps += __shfl_xor(ps, 16);
            ps += __shfl_xor(ps, 32);
            l += ps;

            // ---- P -> B-fragment layout, two 32-wide halves ----
            short8 pf0 = redist(pbf2(p[0][0], p[0][1]), pbf2(p[0][2], p[0][3]),
                                pbf2(p[1][0], p[1][1]), pbf2(p[1][2], p[1][3]), g, c);
            short8 pf1 = redist(pbf2(p[2][0], p[2][1]), pbf2(p[2][2], p[2][3]),
                                pbf2(p[3][0], p[3][1]), pbf2(p[3][2], p[3][3]), g, c);

            // ---- PV from LDS V ----
#pragma unroll
            for (int kk = 0; kk < 2; ++kk){
                short8 vf[8];
#pragma unroll
                for (int mt = 0; mt < 8; ++mt){
                    const int h = mt*16 + c;
                    vf[mt] = *(const short8*)(vb + h*128 + ((kk*64 + g*16) ^ ((h & 7) << 4)));
                }
                const short8 pf = kk ? pf1 : pf0;
                __builtin_amdgcn_s_setprio(1);
#pragma unroll
                for (int mt = 0; mt < 8; ++mt)
                    acc[mt] = __builtin_amdgcn_mfma_f32_16x16x32_bf16(vf[mt], pf, acc[mt], 0,0,0);
                __builtin_amdgcn_s_setprio(0);
            }

            // ---- write next tile into the other buffer (late, T14) ----
            if (kt < nt - 1){
#pragma unroll
                for (int p2 = 0; p2 < 8; ++p2){
                    const int s = p2*128 + tid;
                    const int r = s >> 4, cb = (s & 15) * 16;
                    *(i32x4*)(lds[cur ^ 1] + r*256 + (cb ^ ((r & 7) << 4))) = kreg[p2];
                    const int h = s >> 3, tb = (s & 7) * 16;
                    *(i32x4*)(lds[cur ^ 1] + 16384 + h*128 + (tb ^ ((h & 7) << 4))) = vreg[p2];
                }
            }
        }

        // ---- epilogue: direct normalized store ----
        const float inv = 1.0f / l;
        float* orow = out + ((size_t)b*DT + q) * DH;
#pragma unroll
        for (int mt = 0; mt < 8; ++mt){
            f32x4 v = acc[mt] * inv;
            *(f32x4*)(orow + mt*16 + 4*g) = v;
        }
    }
}

extern "C" void kernel_launch(void* const* d_in, const int* in_sizes, int n_in,
                              void* d_out, int out_size, void* d_ws, size_t ws_size,
                              hipStream_t stream){
    const float* x  = (const float*)d_in[0];
    const float* Wq = (const float*)d_in[1];
    const float* Wk = (const float*)d_in[2];
    const float* Wv = (const float*)d_in[3];
    float* out = (float*)d_out;

    unsigned short* WTc = (unsigned short*)d_ws;         // [32][4][384][8] bf16
    unsigned short* Qb = WTc + 3 * DH * DC;              // [B*T][H]
    unsigned short* Kb = Qb + (size_t)DB * DT * DH;      // [B*T][H]
    unsigned short* VT = Kb + (size_t)DB * DT * DH;      // [B][H][T]

    hipLaunchKernelGGL(prep_wt_kernel, dim3(1536), dim3(256), 0, stream, Wq, Wk, Wv, WTc);
    hipLaunchKernelGGL(qkv_kernel, dim3(256), dim3(512), 0, stream, x, WTc, Qb, Kb, VT);
    hipLaunchKernelGGL(attn_kernel, dim3(256), dim3(128), 0, stream, Qb, Kb, VT, out);
}